// Round 1
// baseline (327.058 us; speedup 1.0000x reference)
//
#include <hip/hip_runtime.h>
#include <hip/hip_bf16.h>

#define NNODES 500000

// 1 - sigmoid(u) = 1/(1+exp(u)).  exp->inf gives rcp(inf)=0 -> correct limit.
__device__ __forceinline__ float omsig(float u) {
    float e = __expf(u);
    return __builtin_amdgcn_rcpf(1.0f + e);
}

// tanh(v) = 1 - 2/(exp(2v)+1).  Inf-safe at both ends.
__device__ __forceinline__ float tanh_fast(float v) {
    float e = __expf(2.0f * v);
    return 1.0f - 2.0f * __builtin_amdgcn_rcpf(e + 1.0f);
}

__global__ __launch_bounds__(256) void hnn_fused(
    const float* __restrict__ x,
    const float* __restrict__ Wx1, const float* __restrict__ bx1,
    const float* __restrict__ bh1,
    const float* __restrict__ Wx2, const float* __restrict__ bx2,
    const float* __restrict__ bh2,
    const float* __restrict__ lin_w, const float* __restrict__ lin_b,
    const float* __restrict__ grad_w, const float* __restrict__ grad_b,
    float* __restrict__ out)
{
    int n = blockIdx.x * blockDim.x + threadIdx.x;
    if (n >= NNODES) return;

    float2 xv = reinterpret_cast<const float2*>(x)[n];

    // ---- layer 1: 2 -> 32, h=0 => h1 = (1-sig(xz+bhz)) * tanh(xc+bhc) ----
    // Wx1 is [2, 96] row-major; z cols 0..31, c cols 64..95. r-gate unused.
    float a1[32];
#pragma unroll
    for (int j = 0; j < 32; ++j) {
        float u = fmaf(xv.x, Wx1[j],
                  fmaf(xv.y, Wx1[96 + j], bx1[j] + bh1[j]));
        float v = fmaf(xv.x, Wx1[64 + j],
                  fmaf(xv.y, Wx1[96 + 64 + j], bx1[64 + j] + bh1[64 + j]));
        float h = omsig(u) * tanh_fast(v);
        a1[j] = fmaxf(h, 0.0f);   // relu
    }

    // ---- layer 2: 32 -> 128 (z and c gates), fused tanh + linear head ----
    // Wx2 is [32, 384] row-major; z cols 0..127, c cols 256..383.
    float hv = lin_b[0];
    for (int k = 0; k < 128; ++k) {
        float u = bx2[k] + bh2[k];
        float v = bx2[256 + k] + bh2[256 + k];
#pragma unroll
        for (int j = 0; j < 32; ++j) {
            u = fmaf(a1[j], Wx2[j * 384 + k],       u);
            v = fmaf(a1[j], Wx2[j * 384 + 256 + k], v);
        }
        float h2 = omsig(u) * tanh_fast(v);
        float a2 = tanh_fast(h2);
        hv = fmaf(a2, lin_w[k], hv);
    }

    // ---- heads: Hval -> dh -> dh @ J.T = (dh1, -dh0) ----
    float d0 = fmaf(hv, grad_w[0], grad_b[0]);
    float d1 = fmaf(hv, grad_w[1], grad_b[1]);
    reinterpret_cast<float2*>(out)[n] = make_float2(d1, -d0);
}

extern "C" void kernel_launch(void* const* d_in, const int* in_sizes, int n_in,
                              void* d_out, int out_size, void* d_ws, size_t ws_size,
                              hipStream_t stream) {
    const float* x      = (const float*)d_in[0];
    // d_in[1] = edge_index : unused (K=1 ChebConv == per-node linear)
    const float* Wx1    = (const float*)d_in[2];
    const float* bx1    = (const float*)d_in[3];
    // d_in[4] = Wh1 : unused (h initialized to zeros)
    const float* bh1    = (const float*)d_in[5];
    const float* Wx2    = (const float*)d_in[6];
    const float* bx2    = (const float*)d_in[7];
    // d_in[8] = Wh2 : unused
    const float* bh2    = (const float*)d_in[9];
    const float* lin_w  = (const float*)d_in[10];
    const float* lin_b  = (const float*)d_in[11];
    const float* grad_w = (const float*)d_in[12];
    const float* grad_b = (const float*)d_in[13];
    float* out = (float*)d_out;

    const int threads = 256;
    const int blocks  = (NNODES + threads - 1) / threads;
    hnn_fused<<<blocks, threads, 0, stream>>>(
        x, Wx1, bx1, bh1, Wx2, bx2, bh2,
        lin_w, lin_b, grad_w, grad_b, out);
}

// Round 2
// 178.757 us; speedup vs baseline: 1.8296x; 1.8296x over previous
//
#include <hip/hip_runtime.h>
#include <hip/hip_bf16.h>

#define NNODES 500000

// 1 - sigmoid(u) = 1/(1+exp(u)).  exp->inf gives rcp(inf)=0 -> correct limit.
__device__ __forceinline__ float omsig(float u) {
    float e = __expf(u);
    return __builtin_amdgcn_rcpf(1.0f + e);
}

// tanh(v) = 1 - 2/(exp(2v)+1).  Inf-safe at both ends.
__device__ __forceinline__ float tanh_fast(float v) {
    float e = __expf(2.0f * v);
    return 1.0f - 2.0f * __builtin_amdgcn_rcpf(e + 1.0f);
}

// Pre-pass: transpose the live columns of Wx2 into [k][z0..z31 | c0..c31]
// (64 contiguous floats per k) and pre-fold biases bz/bc.
// ws layout: [0 .. 8191]  = Wt[k*64 + {j | 32+j}]
//            [8192..8447] = bzc[k] (k<128: z-bias; k>=128: c-bias)
__global__ __launch_bounds__(256) void hnn_prep(
    const float* __restrict__ Wx2,
    const float* __restrict__ bx2,
    const float* __restrict__ bh2,
    float* __restrict__ wsf)
{
    int t = blockIdx.x * blockDim.x + threadIdx.x;
    if (t < 8192) {
        int k = t >> 6;                    // 0..127
        int q = t & 63;                    // 0..63
        int j = q & 31;                    // 0..31
        int col = (q < 32) ? k : (256 + k);
        wsf[t] = Wx2[j * 384 + col];
    }
    if (t < 256) {
        int c = (t < 128) ? t : (256 + (t & 127));
        wsf[8192 + t] = bx2[c] + bh2[c];
    }
}

__global__ __launch_bounds__(256, 4) void hnn_fused(
    const float* __restrict__ x,
    const float* __restrict__ Wx1, const float* __restrict__ bx1,
    const float* __restrict__ bh1,
    const float* __restrict__ wsf,          // transposed weights + folded biases
    const float* __restrict__ lin_w, const float* __restrict__ lin_b,
    const float* __restrict__ grad_w, const float* __restrict__ grad_b,
    float* __restrict__ out)
{
    int n = blockIdx.x * blockDim.x + threadIdx.x;
    if (n >= NNODES) return;

    float2 xv = reinterpret_cast<const float2*>(x)[n];

    // ---- layer 1: 2 -> 32, h=0 => h1 = (1-sig(xz+bhz)) * tanh(xc+bhc) ----
    // Wx1 is [2, 96] row-major; z cols 0..31, c cols 64..95. r-gate unused.
    // j-contiguous streams -> compiler merges into wide s_loads already.
    float a1[32];
#pragma unroll
    for (int j = 0; j < 32; ++j) {
        float u = fmaf(xv.x, Wx1[j],
                  fmaf(xv.y, Wx1[96 + j], bx1[j] + bh1[j]));
        float v = fmaf(xv.x, Wx1[64 + j],
                  fmaf(xv.y, Wx1[96 + 64 + j], bx1[64 + j] + bh1[64 + j]));
        float h = omsig(u) * tanh_fast(v);
        a1[j] = fmaxf(h, 0.0f);   // relu
    }

    // ---- layer 2: 32 -> 128 (z & c gates) + tanh + linear head, fused ----
    // Per k: 64 CONTIGUOUS uniform dwords -> ~4 s_load_dwordx16.
    const float* __restrict__ bzc = wsf + 8192;
    float hv = lin_b[0];
#pragma unroll 2
    for (int k = 0; k < 128; ++k) {
        const float* __restrict__ w = wsf + k * 64;
        float u = bzc[k];
        float v = bzc[128 + k];
#pragma unroll
        for (int j = 0; j < 32; ++j) {
            u = fmaf(a1[j], w[j],      u);
            v = fmaf(a1[j], w[32 + j], v);
        }
        float h2 = omsig(u) * tanh_fast(v);
        float a2 = tanh_fast(h2);
        hv = fmaf(a2, lin_w[k], hv);
    }

    // ---- heads: Hval -> dh -> dh @ J.T = (dh1, -dh0) ----
    float d0 = fmaf(hv, grad_w[0], grad_b[0]);
    float d1 = fmaf(hv, grad_w[1], grad_b[1]);
    reinterpret_cast<float2*>(out)[n] = make_float2(d1, -d0);
}

extern "C" void kernel_launch(void* const* d_in, const int* in_sizes, int n_in,
                              void* d_out, int out_size, void* d_ws, size_t ws_size,
                              hipStream_t stream) {
    const float* x      = (const float*)d_in[0];
    // d_in[1] = edge_index : unused (K=1 ChebConv == per-node linear)
    const float* Wx1    = (const float*)d_in[2];
    const float* bx1    = (const float*)d_in[3];
    // d_in[4] = Wh1 : unused (h initialized to zeros)
    const float* bh1    = (const float*)d_in[5];
    const float* Wx2    = (const float*)d_in[6];
    const float* bx2    = (const float*)d_in[7];
    // d_in[8] = Wh2 : unused
    const float* bh2    = (const float*)d_in[9];
    const float* lin_w  = (const float*)d_in[10];
    const float* lin_b  = (const float*)d_in[11];
    const float* grad_w = (const float*)d_in[12];
    const float* grad_b = (const float*)d_in[13];
    float* out = (float*)d_out;
    float* wsf = (float*)d_ws;   // needs (8192+256)*4 = 33.8 KB

    hnn_prep<<<32, 256, 0, stream>>>(Wx2, bx2, bh2, wsf);

    const int threads = 256;
    const int blocks  = (NNODES + threads - 1) / threads;
    hnn_fused<<<blocks, threads, 0, stream>>>(
        x, Wx1, bx1, bh1, wsf,
        lin_w, lin_b, grad_w, grad_b, out);
}

// Round 3
// 71.573 us; speedup vs baseline: 4.5696x; 2.4975x over previous
//
#include <hip/hip_runtime.h>
#include <hip/hip_bf16.h>

#define NNODES 500000

typedef _Float16 f16x8 __attribute__((ext_vector_type(8)));
typedef float    f32x4 __attribute__((ext_vector_type(4)));

// 1 - sigmoid(u) = 1/(1+exp(u)).  exp->inf gives rcp(inf)=0 -> correct limit.
__device__ __forceinline__ float omsig(float u) {
    float e = __expf(u);
    return __builtin_amdgcn_rcpf(1.0f + e);
}
// tanh(v) = 1 - 2/(exp(2v)+1).  Inf-safe at both ends.
__device__ __forceinline__ float tanh_fast(float v) {
    float e = __expf(2.0f * v);
    return 1.0f - 2.0f * __builtin_amdgcn_rcpf(e + 1.0f);
}

// ---------------------------------------------------------------------------
// Prep: pack layer-2 live gate columns of Wx2 into fp16 MFMA B-fragments.
//   B-frag layout (16x16x32): lane holds B[k][col], col=lane&15, k=(lane>>4)*8+e
//   tile t<8 : z-gate cols t*16+c      (Wx2 col index t*16+c)
//   tile t>=8: c-gate cols (t-8)*16+c  (Wx2 col index 256+(t-8)*16+c)
// ws layout: [0,16384)B  = wsB : _Float16[16][64][8]
//            [16384,+1KB)= bzc : float[256]  (z-bias 0..127 | c-bias 128..255)
// ---------------------------------------------------------------------------
__global__ __launch_bounds__(256) void hnn_prep(
    const float* __restrict__ Wx2, const float* __restrict__ bx2,
    const float* __restrict__ bh2, void* __restrict__ ws)
{
    int t = blockIdx.x * blockDim.x + threadIdx.x;
    _Float16* wsB = (_Float16*)ws;
    float* bzc = (float*)((char*)ws + 16384);
    if (t < 1024) {
        int tile = t >> 6, lane = t & 63;
        int col = (tile < 8) ? tile * 16 + (lane & 15)
                             : 256 + (tile - 8) * 16 + (lane & 15);
        int k0 = (lane >> 4) * 8;
        f16x8 v;
#pragma unroll
        for (int e = 0; e < 8; ++e) v[e] = (_Float16)Wx2[(k0 + e) * 384 + col];
        *(f16x8*)(wsB + t * 8) = v;
    } else if (t < 1280) {
        int i = t - 1024;
        int c = (i < 128) ? i : (256 + (i & 127));
        bzc[i] = bx2[c] + bh2[c];
    }
}

// ---------------------------------------------------------------------------
// Main: 256 threads = 4 waves; each wave owns 64 nodes (4 M-tiles of 16).
// Layer 1 (2->32) per-lane fp32 VALU; layer 2 (32->256 gates) via MFMA fp16;
// gate nonlinearity + lin head fused in C/D layout; shfl_xor row-reduction.
// ---------------------------------------------------------------------------
__global__ __launch_bounds__(256, 2) void hnn_main(
    const float* __restrict__ x,
    const float* __restrict__ Wx1, const float* __restrict__ bx1,
    const float* __restrict__ bh1,
    const void* __restrict__ ws,
    const float* __restrict__ lin_w, const float* __restrict__ lin_b,
    const float* __restrict__ grad_w, const float* __restrict__ grad_b,
    float* __restrict__ out)
{
    const _Float16* wsB = (const _Float16*)ws;
    const float* bzc = (const float*)((const char*)ws + 16384);

    // 4 waves x 64 rows x 40 halfs (32 data + 8 pad -> 80B row stride:
    // bank stride 20, gcd(20,32)=4 -> b128 reads are <=2-way, free)
    __shared__ _Float16 lds[4 * 64 * 40];

    int tid = threadIdx.x;
    int wid = tid >> 6, lane = tid & 63;
    int nodeBase = blockIdx.x * 256 + wid * 64;
    int n = nodeBase + lane;

    float2 xv = (n < NNODES) ? reinterpret_cast<const float2*>(x)[n]
                             : make_float2(0.f, 0.f);

    // ---- layer 1: 2 -> 32, h=0 => a1 = relu((1-sig(xz+bhz))*tanh(xc+bhc)) ----
    float a1[32];
#pragma unroll
    for (int j = 0; j < 32; ++j) {
        float u = fmaf(xv.x, Wx1[j],
                  fmaf(xv.y, Wx1[96 + j], bx1[j] + bh1[j]));
        float v = fmaf(xv.x, Wx1[64 + j],
                  fmaf(xv.y, Wx1[160 + j], bx1[64 + j] + bh1[64 + j]));
        a1[j] = fmaxf(omsig(u) * tanh_fast(v), 0.0f);
    }

    // ---- stage a1 (fp16) into this wave's LDS rows ----
    _Float16* row = lds + (wid * 64 + lane) * 40;
#pragma unroll
    for (int c = 0; c < 4; ++c) {
        f16x8 v;
#pragma unroll
        for (int e = 0; e < 8; ++e) v[e] = (_Float16)a1[c * 8 + e];
        *(f16x8*)(row + c * 8) = v;
    }
    __syncthreads();

    // ---- A-fragments: row=lane&15 (node within tile), k=(lane>>4)*8+e ----
    f16x8 afrag[4];
    const _Float16* base = lds + wid * 64 * 40;
#pragma unroll
    for (int mt = 0; mt < 4; ++mt)
        afrag[mt] = *(const f16x8*)(base + (mt * 16 + (lane & 15)) * 40
                                         + (lane >> 4) * 8);

    const f32x4 zero = {0.f, 0.f, 0.f, 0.f};
    float hvp[4][4] = {};   // all indices compile-time (unrolled) -> stays in regs

#pragma unroll
    for (int p = 0; p < 8; ++p) {
        f16x8 bz = *(const f16x8*)(wsB + (p * 64 + lane) * 8);
        f16x8 bc = *(const f16x8*)(wsB + ((8 + p) * 64 + lane) * 8);
        float bzv = bzc[p * 16 + (lane & 15)];
        float bcv = bzc[128 + p * 16 + (lane & 15)];
        float lwv = lin_w[p * 16 + (lane & 15)];
#pragma unroll
        for (int mt = 0; mt < 4; ++mt) {
            f32x4 az = __builtin_amdgcn_mfma_f32_16x16x32_f16(afrag[mt], bz, zero, 0, 0, 0);
            f32x4 ac = __builtin_amdgcn_mfma_f32_16x16x32_f16(afrag[mt], bc, zero, 0, 0, 0);
#pragma unroll
            for (int r = 0; r < 4; ++r) {
                float u = az[r] + bzv;
                float v = ac[r] + bcv;
                float h2 = omsig(u) * tanh_fast(v);
                float a2 = tanh_fast(h2);
                hvp[mt][r] = fmaf(a2, lwv, hvp[mt][r]);
            }
        }
    }

    // ---- reduce over the 16 cols (lanes within 16-group), then heads ----
    float lb = lin_b[0];
    float gw0 = grad_w[0], gw1 = grad_w[1];
    float gb0 = grad_b[0], gb1 = grad_b[1];
#pragma unroll
    for (int mt = 0; mt < 4; ++mt) {
#pragma unroll
        for (int r = 0; r < 4; ++r) {
            float s = hvp[mt][r];
            s += __shfl_xor(s, 1);
            s += __shfl_xor(s, 2);
            s += __shfl_xor(s, 4);
            s += __shfl_xor(s, 8);
            hvp[mt][r] = s;   // every lane in the 16-group now has the full sum
        }
        if ((lane & 15) < 4) {
            int r = lane & 3;  // writer lane w writes row-reg r=w (static select)
            float s = (r == 0) ? hvp[mt][0] : (r == 1) ? hvp[mt][1]
                    : (r == 2) ? hvp[mt][2] : hvp[mt][3];
            float hv = s + lb;
            float d0 = fmaf(hv, gw0, gb0);
            float d1 = fmaf(hv, gw1, gb1);
            int node = nodeBase + mt * 16 + (lane >> 4) * 4 + r;
            if (node < NNODES)
                reinterpret_cast<float2*>(out)[node] = make_float2(d1, -d0);
        }
    }
}

extern "C" void kernel_launch(void* const* d_in, const int* in_sizes, int n_in,
                              void* d_out, int out_size, void* d_ws, size_t ws_size,
                              hipStream_t stream) {
    const float* x      = (const float*)d_in[0];
    // d_in[1] = edge_index : unused (K=1 ChebConv == per-node linear)
    const float* Wx1    = (const float*)d_in[2];
    const float* bx1    = (const float*)d_in[3];
    // d_in[4] = Wh1 : unused (h initialized to zeros)
    const float* bh1    = (const float*)d_in[5];
    const float* Wx2    = (const float*)d_in[6];
    const float* bx2    = (const float*)d_in[7];
    // d_in[8] = Wh2 : unused
    const float* bh2    = (const float*)d_in[9];
    const float* lin_w  = (const float*)d_in[10];
    const float* lin_b  = (const float*)d_in[11];
    const float* grad_w = (const float*)d_in[12];
    const float* grad_b = (const float*)d_in[13];
    float* out = (float*)d_out;

    hnn_prep<<<5, 256, 0, stream>>>(Wx2, bx2, bh2, d_ws);

    const int threads = 256;
    const int blocks  = (NNODES + threads - 1) / threads;  // 1954
    hnn_main<<<blocks, threads, 0, stream>>>(
        x, Wx1, bx1, bh1, d_ws,
        lin_w, lin_b, grad_w, grad_b, out);
}

// Round 5
// 69.386 us; speedup vs baseline: 4.7136x; 1.0315x over previous
//
#include <hip/hip_runtime.h>
#include <hip/hip_bf16.h>
#include <math.h>

#define NNODES 500000
#define TAB_N 1025            // entries 0..1024 over x in [-16,16], step 1/32

typedef _Float16 f16x8 __attribute__((ext_vector_type(8)));
typedef float    f32x4 __attribute__((ext_vector_type(4)));

// ---------------------------------------------------------------------------
// ws layout:
//   [0,16384)        wsB  : _Float16[16][64][8]  MFMA B-fragments (z|c gates)
//   [16384,17408)    bzc  : float[256]           folded biases (z | c)
//   [17408,25608)    tab  : float[2*TAB_N]       (tanh(x_i), tanh(x_{i+1})-tanh(x_i))
// ---------------------------------------------------------------------------
__global__ __launch_bounds__(256) void hnn_prep(
    const float* __restrict__ Wx2, const float* __restrict__ bx2,
    const float* __restrict__ bh2, void* __restrict__ ws)
{
    int t = blockIdx.x * blockDim.x + threadIdx.x;
    _Float16* wsB = (_Float16*)ws;
    float* bzc = (float*)((char*)ws + 16384);
    float* tab = (float*)((char*)ws + 17408);
    if (t < 1024) {
        // B-frag (16x16x32): lane holds B[k][col], col=lane&15, k=(lane>>4)*8+e
        int tile = t >> 6, lane = t & 63;
        int col = (tile < 8) ? tile * 16 + (lane & 15)
                             : 256 + (tile - 8) * 16 + (lane & 15);
        int k0 = (lane >> 4) * 8;
        f16x8 v;
#pragma unroll
        for (int e = 0; e < 8; ++e) v[e] = (_Float16)Wx2[(k0 + e) * 384 + col];
        *(f16x8*)(wsB + t * 8) = v;
    } else if (t < 1280) {
        int i = t - 1024;
        int c = (i < 128) ? i : (256 + (i & 127));
        bzc[i] = bx2[c] + bh2[c];
    } else if (t < 1280 + TAB_N) {
        int i = t - 1280;
        float x0 = (float)(i - 512) * (1.0f / 32.0f);
        float y0 = tanhf(x0);
        float y1 = tanhf(x0 + (1.0f / 32.0f));
        tab[2 * i]     = y0;
        tab[2 * i + 1] = y1 - y0;
    }
}

// tanh via LDS LUT + linear interp. scale=32 -> tanh(x); scale=16 -> tanh(x/2).
__device__ __forceinline__ float tanh_lut(const float* __restrict__ tab,
                                          float x, float scale) {
    float t = fmaf(x, scale, 512.0f);
    t = fminf(fmaxf(t, 0.0f), 1023.0f);
    int i = (int)t;                 // t >= 0 -> trunc == floor
    float fr = t - (float)i;
    float2 p = *(const float2*)(tab + 2 * i);   // ds_read_b64: (y, slope)
    return fmaf(fr, p.y, p.x);
}

// ---------------------------------------------------------------------------
// 256 threads = 4 waves; each wave owns 64 nodes (4 M-tiles of 16).
// Layer 1 on VALU with LUT gates; layer 2 matmul on MFMA fp16 with biases in
// the C operand; gate nonlinearities via LUT; shfl_xor column reduction.
// ---------------------------------------------------------------------------
__global__ __launch_bounds__(256, 2) void hnn_main(
    const float* __restrict__ x,
    const float* __restrict__ Wx1, const float* __restrict__ bx1,
    const float* __restrict__ bh1,
    const void* __restrict__ ws,
    const float* __restrict__ lin_w, const float* __restrict__ lin_b,
    const float* __restrict__ grad_w, const float* __restrict__ grad_b,
    float* __restrict__ out)
{
    const _Float16* wsB = (const _Float16*)ws;
    const float* bzc = (const float*)((const char*)ws + 16384);
    const float* wst = (const float*)((const char*)ws + 17408);

    // a1 staging: 4 waves x 64 rows x 40 halfs (80B row stride: 16B-aligned
    // for b128, bank stride 20 -> 2-way max on b128 reads = free)
    __shared__ _Float16 a1s[4 * 64 * 40];
    __shared__ float tab[2 * TAB_N];

    int tid = threadIdx.x;
    int wid = tid >> 6, lane = tid & 63;
    int nodeBase = blockIdx.x * 256 + wid * 64;
    int n = nodeBase + lane;

    // stage LUT global -> LDS
    for (int idx = tid; idx < 2 * TAB_N; idx += 256) tab[idx] = wst[idx];
    __syncthreads();

    float2 xv = (n < NNODES) ? reinterpret_cast<const float2*>(x)[n]
                             : make_float2(0.f, 0.f);

    // ---- layer 1: 2 -> 32 ; a1 = relu((1-sig(u)) * tanh(v)) ----
    float a1[32];
#pragma unroll
    for (int j = 0; j < 32; ++j) {
        float u = fmaf(xv.x, Wx1[j],
                  fmaf(xv.y, Wx1[96 + j], bx1[j] + bh1[j]));
        float v = fmaf(xv.x, Wx1[64 + j],
                  fmaf(xv.y, Wx1[160 + j], bx1[64 + j] + bh1[64 + j]));
        float tz = tanh_lut(tab, u, 16.0f);        // tanh(u/2)
        float tc = tanh_lut(tab, v, 32.0f);        // tanh(v)
        float h = fmaf(tz, -0.5f, 0.5f) * tc;      // (1-sig(u))*tanh(v)
        a1[j] = fmaxf(h, 0.0f);
    }

    // ---- stage a1 (fp16) into this wave's LDS rows ----
    _Float16* row = a1s + (wid * 64 + lane) * 40;
#pragma unroll
    for (int c = 0; c < 4; ++c) {
        f16x8 v;
#pragma unroll
        for (int e = 0; e < 8; ++e) v[e] = (_Float16)a1[c * 8 + e];
        *(f16x8*)(row + c * 8) = v;
    }
    __syncthreads();

    // ---- A-fragments: row=lane&15 (node), k=(lane>>4)*8+e ----
    f16x8 afrag[4];
    const _Float16* base = a1s + wid * 64 * 40;
#pragma unroll
    for (int mt = 0; mt < 4; ++mt)
        afrag[mt] = *(const f16x8*)(base + (mt * 16 + (lane & 15)) * 40
                                         + (lane >> 4) * 8);

    float hvp[4][4] = {};   // static indices only (fully unrolled)

#pragma unroll
    for (int p = 0; p < 8; ++p) {
        f16x8 bzf = *(const f16x8*)(wsB + (p * 64 + lane) * 8);
        f16x8 bcf = *(const f16x8*)(wsB + ((8 + p) * 64 + lane) * 8);
        float bzv = bzc[p * 16 + (lane & 15)];
        float bcv = bzc[128 + p * 16 + (lane & 15)];
        float lwv = lin_w[p * 16 + (lane & 15)];
        f32x4 cz = {bzv, bzv, bzv, bzv};
        f32x4 cc = {bcv, bcv, bcv, bcv};
#pragma unroll
        for (int mt = 0; mt < 4; ++mt) {
            f32x4 az = __builtin_amdgcn_mfma_f32_16x16x32_f16(afrag[mt], bzf, cz, 0, 0, 0);
            f32x4 ac = __builtin_amdgcn_mfma_f32_16x16x32_f16(afrag[mt], bcf, cc, 0, 0, 0);
#pragma unroll
            for (int r = 0; r < 4; ++r) {
                float tz = tanh_lut(tab, az[r], 16.0f);    // tanh(u/2)
                float tc = tanh_lut(tab, ac[r], 32.0f);    // tanh(v)
                float h2 = fmaf(tz, -0.5f, 0.5f) * tc;
                float a2 = tanh_lut(tab, h2, 32.0f);       // tanh(h2)
                hvp[mt][r] = fmaf(a2, lwv, hvp[mt][r]);
            }
        }
    }

    // ---- reduce over 16 cols (shfl within 16-groups), then heads ----
    float lb = lin_b[0];
    float gw0 = grad_w[0], gw1 = grad_w[1];
    float gb0 = grad_b[0], gb1 = grad_b[1];
#pragma unroll
    for (int mt = 0; mt < 4; ++mt) {
#pragma unroll
        for (int r = 0; r < 4; ++r) {
            float s = hvp[mt][r];
            s += __shfl_xor(s, 1);
            s += __shfl_xor(s, 2);
            s += __shfl_xor(s, 4);
            s += __shfl_xor(s, 8);
            hvp[mt][r] = s;
        }
        if ((lane & 15) < 4) {
            int r = lane & 3;
            float s = (r == 0) ? hvp[mt][0] : (r == 1) ? hvp[mt][1]
                    : (r == 2) ? hvp[mt][2] : hvp[mt][3];
            float hv = s + lb;
            float d0 = fmaf(hv, gw0, gb0);
            float d1 = fmaf(hv, gw1, gb1);
            int node = nodeBase + mt * 16 + (lane >> 4) * 4 + r;
            if (node < NNODES)
                reinterpret_cast<float2*>(out)[node] = make_float2(d1, -d0);
        }
    }
}

extern "C" void kernel_launch(void* const* d_in, const int* in_sizes, int n_in,
                              void* d_out, int out_size, void* d_ws, size_t ws_size,
                              hipStream_t stream) {
    const float* x      = (const float*)d_in[0];
    // d_in[1] = edge_index : unused (K=1 ChebConv == per-node linear)
    const float* Wx1    = (const float*)d_in[2];
    const float* bx1    = (const float*)d_in[3];
    // d_in[4] = Wh1 : unused (h initialized to zeros)
    const float* bh1    = (const float*)d_in[5];
    const float* Wx2    = (const float*)d_in[6];
    const float* bx2    = (const float*)d_in[7];
    // d_in[8] = Wh2 : unused
    const float* bh2    = (const float*)d_in[9];
    const float* lin_w  = (const float*)d_in[10];
    const float* lin_b  = (const float*)d_in[11];
    const float* grad_w = (const float*)d_in[12];
    const float* grad_b = (const float*)d_in[13];
    float* out = (float*)d_out;

    hnn_prep<<<10, 256, 0, stream>>>(Wx2, bx2, bh2, d_ws);

    const int threads = 256;
    const int blocks  = (NNODES + threads - 1) / threads;  // 1954
    hnn_main<<<blocks, threads, 0, stream>>>(
        x, Wx1, bx1, bh1, d_ws,
        lin_w, lin_b, grad_w, grad_b, out);
}